// Round 11
// baseline (50.397 us; speedup 1.0000x reference)
//
#include <hip/hip_runtime.h>
#include <math.h>

#define H 8
#define DK 16
#define OUTC 128
#define INC 64
#define NB 16
#define NN 256
#define NM 128

typedef float f32x4 __attribute__((ext_vector_type(4)));
typedef short s16x4 __attribute__((ext_vector_type(4)));
typedef short s16x8 __attribute__((ext_vector_type(8)));

#if __has_builtin(__builtin_amdgcn_mfma_f32_16x16x16bf16_1k)
__device__ __forceinline__ f32x4 MFMA16(s16x4 a, s16x4 b, f32x4 c) {
    return __builtin_amdgcn_mfma_f32_16x16x16bf16_1k(a, b, c, 0, 0, 0);
}
#else
__device__ __forceinline__ f32x4 MFMA16(s16x4 a, s16x4 b, f32x4 c) {
    s16x8 a8 = {a[0], a[1], a[2], a[3], 0, 0, 0, 0};
    s16x8 b8 = {b[0], b[1], b[2], b[3], 0, 0, 0, 0};
    return __builtin_amdgcn_mfma_f32_16x16x32_bf16(a8, b8, c, 0, 0, 0);
}
#endif

__device__ __forceinline__ unsigned short f2bf(float x) {   // RNE (weights/q/k/v packs)
    unsigned int u = __float_as_uint(x);
    return (unsigned short)((u + 0x7fffu + ((u >> 16) & 1u)) >> 16);
}
__device__ __forceinline__ float bf2f(unsigned short s) {
    return __uint_as_float(((unsigned int)s) << 16);
}

struct KArgs {
    const float* h_dst; const float* h_src; const float* h_edge;
    const int* adj_ma; const int* adj_oo;
    const float* Wq; const float* bq; const float* Wk; const float* bk;
    const float* Wkd; const float* bkd; const float* Wke; const float* bke;
    const float* Wv; const float* bv; const float* Wvd; const float* bvd;
    const float* Wa; const float* ba;
    const float* rel_pri; const float* rel_att; const float* rel_msg;
    const float* skip;
    float* qbuf; unsigned short* qpk; unsigned short* kpk; unsigned short* vpk;
    unsigned short* gelf; unsigned short* Wab;
    float* outp;
};

// ---------------------------------------------------------------------------
// Kernel 1: projections (1024 blocks x 16 rows; 4 blocks/CU) + Wab pack
// (block 1024). Layouts as round 10:
//   qpk/kpk: MFMA frags; vpk: B-frags [bh][t:24][lane][slot]
//   Wab: bf16 B-frags [ct:8][kt:8][lane:64][4]
// ---------------------------------------------------------------------------
__global__ __launch_bounds__(256) void proj_k(KArgs A)
{
    __shared__ float X_s[16 * 68];
    __shared__ float WT_s[64 * 128];

    int t = threadIdx.x;
    int unit = blockIdx.x;

    if (unit >= 1024) {
        // ---- Wab pack: Wa -> bf16 B-frags ----
        #pragma unroll
        for (int it = 0; it < 16; ++it) {
            int flat = t + 256 * it;             // 0..4095
            int ct = flat >> 9, kt = (flat >> 6) & 7, l = flat & 63;
            int co = ct * 16 + (l & 15);
            int kb = kt * 16 + ((l >> 4) << 2);
            float4 wv = *(const float4*)(A.Wa + (long)co * OUTC + kb);
            unsigned int lo = (unsigned int)f2bf(wv.x) | ((unsigned int)f2bf(wv.y) << 16);
            unsigned int hi = (unsigned int)f2bf(wv.z) | ((unsigned int)f2bf(wv.w) << 16);
            ((uint2*)A.Wab)[(ct*8 + kt)*64 + l] = make_uint2(lo, hi);
        }
        return;
    }

    int type, grow0;
    const float *X, *W, *bias;
    if (unit < 256)       { type = 0; grow0 = unit * 16;        X = A.h_dst; W = A.Wq;  bias = A.bq;  }
    else if (unit < 512)  { type = 2; grow0 = (unit-256) * 16;  X = A.h_dst; W = A.Wkd; bias = A.bkd; }
    else if (unit < 768)  { type = 4; grow0 = (unit-512) * 16;  X = A.h_dst; W = A.Wvd; bias = A.bvd; }
    else if (unit < 896)  { type = 1; grow0 = (unit-768) * 16;  X = A.h_src; W = A.Wk;  bias = A.bk;  }
    else                  { type = 3; grow0 = (unit-896) * 16;  X = A.h_src; W = A.Wv;  bias = A.bv;  }

    {
        int row = t >> 4, part = t & 15;         // 256 float4 = 16 rows x 16
        float4 v = *(const float4*)(X + (long)(grow0 + row) * INC + part * 4);
        *(float4*)(X_s + row * 68 + part * 4) = v;
    }
    #pragma unroll
    for (int p = 0; p < 8; ++p) {
        int idx = t + 256 * p;
        int o = idx >> 4, part = idx & 15;
        float4 v = *(const float4*)(W + (long)o * INC + part * 4);
        int q0 = o >> 2, ob = o & 3;
        WT_s[(part*4+0)*128 + (((q0 ^ ((part*4+0)&31))<<2) + ob)] = v.x;
        WT_s[(part*4+1)*128 + (((q0 ^ ((part*4+1)&31))<<2) + ob)] = v.y;
        WT_s[(part*4+2)*128 + (((q0 ^ ((part*4+2)&31))<<2) + ob)] = v.z;
        WT_s[(part*4+3)*128 + (((q0 ^ ((part*4+3)&31))<<2) + ob)] = v.w;
    }
    __syncthreads();

    int o4 = t & 31;
    int rq = t >> 5;
    float4 acc[2];
    acc[0] = make_float4(0.f, 0.f, 0.f, 0.f);
    acc[1] = make_float4(0.f, 0.f, 0.f, 0.f);

    #pragma unroll 4
    for (int i4 = 0; i4 < 16; ++i4) {
        float4 w0 = *(const float4*)(WT_s + (i4*4+0)*128 + ((o4 ^ ((i4*4+0)&31))<<2));
        float4 w1 = *(const float4*)(WT_s + (i4*4+1)*128 + ((o4 ^ ((i4*4+1)&31))<<2));
        float4 w2 = *(const float4*)(WT_s + (i4*4+2)*128 + ((o4 ^ ((i4*4+2)&31))<<2));
        float4 w3 = *(const float4*)(WT_s + (i4*4+3)*128 + ((o4 ^ ((i4*4+3)&31))<<2));
        #pragma unroll
        for (int rr = 0; rr < 2; ++rr) {
            float4 x = *(const float4*)(X_s + (rq + 8*rr) * 68 + i4*4);
            acc[rr].x += x.x*w0.x + x.y*w1.x + x.z*w2.x + x.w*w3.x;
            acc[rr].y += x.x*w0.y + x.y*w1.y + x.z*w2.y + x.w*w3.y;
            acc[rr].z += x.x*w0.z + x.y*w1.z + x.z*w2.z + x.w*w3.z;
            acc[rr].w += x.x*w0.w + x.y*w1.w + x.z*w2.w + x.w*w3.w;
        }
    }

    int obase = o4 * 4;
    int head = o4 >> 2;
    float4 bs = *(const float4*)(bias + obase);
    float scl[4];
    #pragma unroll
    for (int c = 0; c < 4; ++c) {
        int o = obase + c;
        int hh = o >> 4, d = o & 15;
        float v = 1.f;
        if (type == 1)      v = A.rel_pri[hh]     * 0.25f * A.rel_att[(hh*DK + d)*DK + d];
        else if (type == 2) v = A.rel_pri[H + hh] * 0.25f * A.rel_att[((H + hh)*DK + d)*DK + d];
        else if (type == 3) v = A.rel_msg[(hh*DK + d)*DK + d];
        else if (type == 4) v = A.rel_msg[((H + hh)*DK + d)*DK + d];
        scl[c] = v;
    }
    #pragma unroll
    for (int rr = 0; rr < 2; ++rr) {
        int grow = grow0 + rq + 8*rr;
        float4 r4;
        r4.x = (acc[rr].x + bs.x) * scl[0];
        r4.y = (acc[rr].y + bs.y) * scl[1];
        r4.z = (acc[rr].z + bs.z) * scl[2];
        r4.w = (acc[rr].w + bs.w) * scl[3];
        if (type == 0) {
            *(float4*)(A.qbuf + (long)grow * OUTC + obase) = r4;
            unsigned int lo = (unsigned int)f2bf(r4.x) | ((unsigned int)f2bf(r4.y) << 16);
            unsigned int hi = (unsigned int)f2bf(r4.z) | ((unsigned int)f2bf(r4.w) << 16);
            int b = grow >> 8, row = grow & 255;
            int lane = ((o4 & 3) << 4) + (row & 15);
            ((uint2*)A.qpk)[(long)((b*H + head)*16 + (row >> 4)) * 64 + lane] = make_uint2(lo, hi);
        } else if (type == 1 || type == 2) {
            unsigned int lo = (unsigned int)f2bf(r4.x) | ((unsigned int)f2bf(r4.y) << 16);
            unsigned int hi = (unsigned int)f2bf(r4.z) | ((unsigned int)f2bf(r4.w) << 16);
            int b, key;
            if (type == 1) { b = grow >> 7; key = grow & 127; }
            else           { b = grow >> 8; key = 128 + (grow & 255); }
            int lane = (key & 15) + ((o4 & 3) << 4);
            ((uint2*)A.kpk)[(long)((b*H + head)*24 + (key >> 4)) * 64 + lane] = make_uint2(lo, hi);
        } else {
            int b, key;
            if (type == 3) { b = grow >> 7; key = grow & 127; }
            else           { b = grow >> 8; key = 128 + (grow & 255); }
            int tt = key >> 4, lg = (key >> 2) & 3, slot = key & 3;
            int dbase = (o4 & 3) * 4;
            unsigned short* vp = A.vpk + ((long)((b*H + head)*24 + tt) * 64) * 4;
            vp[(lg*16 + dbase+0)*4 + slot] = f2bf(r4.x);
            vp[(lg*16 + dbase+1)*4 + slot] = f2bf(r4.y);
            vp[(lg*16 + dbase+2)*4 + slot] = f2bf(r4.z);
            vp[(lg*16 + dbase+3)*4 + slot] = f2bf(r4.w);
        }
    }
}

// ---------------------------------------------------------------------------
// Kernel 2: attention. 2048 blocks = (b, chunk, head) x 256 threads (4 waves).
// Wave q handles tiles tt = 4i+q (i<6); partials combined via LDS.
// Masks packed in-block via ballot. gel written to global as bf16 A-frags.
// ---------------------------------------------------------------------------
__global__ __launch_bounds__(256) void attn_k(KArgs A)
{
    __shared__ __align__(16) unsigned char smem[19328];
    float* he_s   = (float*)smem;                       // [128][17]  8704 B
    unsigned long long* mk_s = (unsigned long long*)(smem + 8704); // [16][6] 768 B
    float* s1s2_s = (float*)(smem + 9472);              // [16][2]    128 B
    float* stats_s= (float*)(smem + 9600);              // [16][4]    256 B
    float* gel_s  = (float*)(smem + 9856);              // [16][20]   1280 B
    float* ocomb  = (float*)(smem + 11136);             // [4][64][4] 4096 B
    float* scomb  = (float*)(smem + 15232);             // [4][64][4] 4096 B

    int t = threadIdx.x;
    int bid = blockIdx.x;
    int head = bid & 7;
    int chunk = (bid >> 3) & 15;
    int b = bid >> 7;
    int row0 = b * NN + chunk * 16;
    int bh = b * H + head;

    int q = t >> 6, l = t & 63;
    int qi = l & 15;
    int grpb = (l >> 4) << 2;

    // ---- stage h_edge (256 threads x 2 float4) ----
    #pragma unroll
    for (int p = 0; p < 2; ++p) {
        int idx = t + 256 * p;
        int qr = idx >> 5, jc = (idx & 31) << 2;
        float4 v = *(const float4*)(A.h_edge + (long)(row0 + qr) * NM + jc);
        he_s[(jc+0)*17 + qr] = v.x;
        he_s[(jc+1)*17 + qr] = v.y;
        he_s[(jc+2)*17 + qr] = v.z;
        he_s[(jc+3)*17 + qr] = v.w;
    }
    // ---- masks: wave q packs rows 4q..4q+3 ----
    #pragma unroll
    for (int rr = 0; rr < 4; ++rr) {
        int row = q * 4 + rr;
        #pragma unroll
        for (int g = 0; g < 6; ++g) {
            int a = (g < 2) ? A.adj_ma[(long)(row0 + row) * NM + (g << 6) + l]
                            : A.adj_oo[(long)(row0 + row) * NN + ((g - 2) << 6) + l];
            unsigned long long m = __ballot(a != 0);
            if (l == 0) mk_s[row * 6 + g] = m;
        }
    }
    // ---- S1/S2: wave 0, lane = row*4 + dquad ----
    if (t < 64) {
        int row = l >> 2, dq = l & 3;
        float s1 = 0.f, s2 = 0.f;
        #pragma unroll
        for (int j = 0; j < 4; ++j) {
            int d = dq * 4 + j;
            int o = head * DK + d;
            float qq = A.qbuf[(long)(row0 + row) * OUTC + o] * A.rel_att[o * DK + d];
            s1 += qq * A.Wke[o];
            s2 += qq * A.bke[o];
        }
        s1 += __shfl_xor(s1, 1); s1 += __shfl_xor(s1, 2);
        s2 += __shfl_xor(s2, 1); s2 += __shfl_xor(s2, 2);
        if (dq == 0) {
            float sc = A.rel_pri[head] * 0.25f;
            s1s2_s[row*2]     = s1 * sc;
            s1s2_s[row*2 + 1] = s2 * sc;
        }
    }
    __syncthreads();

    union { uint2 u; s16x4 s; } qf;
    qf.u = ((const uint2*)A.qpk)[(long)(bh * 16 + chunk) * 64 + l];
    float S1q = s1s2_s[qi*2], S2q = s1s2_s[qi*2 + 1];

    const unsigned int* mrow = (const unsigned int*)(mk_s + qi * 6);
    const uint2* kbase = (const uint2*)A.kpk + (long)(bh * 24) * 64;
    const uint2* vbase = (const uint2*)A.vpk + (long)(bh * 24) * 64;

    float sum = 0.f, t0 = 0.f, t1 = 0.f, so = 0.f;
    f32x4 O0 = {0.f, 0.f, 0.f, 0.f};
    f32x4 O1 = {0.f, 0.f, 0.f, 0.f};
    const f32x4 zero = {0.f, 0.f, 0.f, 0.f};
    int sb = ((q & 1) << 4) + grpb;
    int dwb = q >> 1;

    #pragma unroll
    for (int i = 0; i < 6; ++i) {
        int tt = 4 * i + q;
        union { uint2 u; s16x4 s; } kf, vf;
        kf.u = kbase[tt * 64 + l];
        vf.u = vbase[tt * 64 + l];
        f32x4 s4 = MFMA16(kf.s, qf.s, zero);

        unsigned int dw = mrow[dwb + 2 * i];
        float ev[4], hev[4];
        #pragma unroll
        for (int r = 0; r < 4; ++r) {
            float x = s4[r];
            if (i < 2) {                     // tt < 8 for all q
                hev[r] = he_s[(tt * 16 + grpb + r) * 17 + qi];
                x += hev[r] * S1q + S2q;
            }
            float lk = fmaxf(x, 0.1f * x);
            float ex = __expf(lk);
            ev[r] = ((dw >> (sb + r)) & 1u) ? ex : 0.f;
        }
        float es = (ev[0] + ev[1]) + (ev[2] + ev[3]);
        sum += es;
        if (i < 2) {
            t0 += es;
            t1 += (ev[0]*hev[0] + ev[1]*hev[1]) + (ev[2]*hev[2] + ev[3]*hev[3]);
        } else {
            so += es;
        }
        // truncation pack (P is positive O(1); bf16-trunc error ~0.4%)
        unsigned int u0 = __float_as_uint(ev[0]), u1 = __float_as_uint(ev[1]);
        unsigned int u2 = __float_as_uint(ev[2]), u3 = __float_as_uint(ev[3]);
        union { uint2 u; s16x4 s; } pp;
        pp.u = make_uint2((u0 >> 16) | (u1 & 0xffff0000u),
                          (u2 >> 16) | (u3 & 0xffff0000u));
        if (i & 1) O1 = MFMA16(pp.s, vf.s, O1);
        else       O0 = MFMA16(pp.s, vf.s, O0);
    }
    f32x4 Op = O0 + O1;

    *(f32x4*)(ocomb + (q*64 + l)*4) = Op;
    {
        float4 sc4 = make_float4(sum, t0, t1, so);
        *(float4*)(scomb + (q*64 + l)*4) = sc4;
    }
    __syncthreads();

    // all waves combine (redundant, but no idle lanes)
    f32x4 O = zero;
    sum = 0.f; t0 = 0.f; t1 = 0.f; so = 0.f;
    #pragma unroll
    for (int qq = 0; qq < 4; ++qq) {
        O = O + *(const f32x4*)(ocomb + (qq*64 + l)*4);
        float4 sc4 = *(const float4*)(scomb + (qq*64 + l)*4);
        sum += sc4.x; t0 += sc4.y; t1 += sc4.z; so += sc4.w;
    }
    sum += __shfl_xor(sum, 16); sum += __shfl_xor(sum, 32);
    t0  += __shfl_xor(t0, 16);  t0  += __shfl_xor(t0, 32);
    t1  += __shfl_xor(t1, 16);  t1  += __shfl_xor(t1, 32);
    so  += __shfl_xor(so, 16);  so  += __shfl_xor(so, 32);
    if (l < 16) {
        float4 st = make_float4(1.f / sum, t0, t1, so);
        *(float4*)(stats_s + l * 4) = st;
    }

    // epilogue (same-wave stats; all waves duplicate identical values)
    {
        int d = qi;
        int o = head * DK + d;
        float a0 = A.rel_att[o * DK + d];
        float wk = A.Wke[o], bk = A.bke[o];
        #pragma unroll
        for (int r = 0; r < 4; ++r) {
            int ql = grpb + r;
            float4 st = *(const float4*)(stats_s + ql * 4);
            int key = 128 + chunk * 16 + ql;
            int tk = key >> 4, lg = (key >> 2) & 3, slot = key & 3;
            float cs = bf2f(A.vpk[(((long)(bh * 24) + tk) * 64 + lg*16 + d) * 4 + slot]);
            float res = st.x * (O[r] + a0 * (wk * st.z + bk * st.y) + st.w * cs);
            gel_s[ql * 20 + d] = 0.5f * res * (1.f + erff(res * 0.70710678118654752f));
        }
    }
    __syncthreads();

    // wave 0: pack gel -> bf16 A-frags in global
    if (q == 0) {
        int row = l & 15, kq = l >> 4;
        float g0 = gel_s[row * 20 + kq*4 + 0];
        float g1 = gel_s[row * 20 + kq*4 + 1];
        float g2 = gel_s[row * 20 + kq*4 + 2];
        float g3 = gel_s[row * 20 + kq*4 + 3];
        unsigned int lo = (unsigned int)f2bf(g0) | ((unsigned int)f2bf(g1) << 16);
        unsigned int hi = (unsigned int)f2bf(g2) | ((unsigned int)f2bf(g3) << 16);
        ((uint2*)A.gelf)[((long)(b*16 + chunk) * 8 + head) * 64 + l] = make_uint2(lo, hi);
    }
}

// ---------------------------------------------------------------------------
// Kernel 3: output GEMM via MFMA. 256 blocks (16-row chunk) x 1024 threads;
// wave = (co-tile ct 0..7, k-half kh 0..1). gelf A-frags + Wab B-frags from L2.
// ---------------------------------------------------------------------------
__global__ __launch_bounds__(1024) void out_k(KArgs A)
{
    __shared__ float ocomb[8 * 64 * 4];

    int t = threadIdx.x;
    int chunkG = blockIdx.x;
    long row0 = (long)chunkG * 16;

    int w = t >> 6, l = t & 63;
    int ct = w & 7, kh = w >> 3;
    int grpb = (l >> 4) << 2;

    f32x4 Cp = {0.f, 0.f, 0.f, 0.f};
    #pragma unroll
    for (int kk = 0; kk < 4; ++kk) {
        int kt = kh * 4 + kk;
        union { uint2 u; s16x4 s; } af, bf;
        af.u = ((const uint2*)A.gelf)[((long)chunkG * 8 + kt) * 64 + l];
        bf.u = ((const uint2*)A.Wab)[(ct*8 + kt) * 64 + l];
        Cp = MFMA16(af.s, bf.s, Cp);
    }
    if (kh) *(f32x4*)(ocomb + (ct*64 + l)*4) = Cp;
    __syncthreads();
    if (!kh) {
        f32x4 Co = *(const f32x4*)(ocomb + (ct*64 + l)*4);
        Cp = Cp + Co;
        float alpha = 1.f / (1.f + __expf(-A.skip[0]));
        float beta = 1.f - alpha;
        int co = ct * 16 + (l & 15);
        float bias = A.ba[co];
        #pragma unroll
        for (int r = 0; r < 4; ++r) {
            long grow = row0 + grpb + r;
            float q0 = A.qbuf[grow * OUTC + co];
            A.outp[grow * OUTC + co] = alpha * (Cp[r] + bias) + beta * q0;
        }
    }
}

extern "C" void kernel_launch(void* const* d_in, const int* in_sizes, int n_in,
                              void* d_out, int out_size, void* d_ws, size_t ws_size,
                              hipStream_t stream) {
    char* ws = (char*)d_ws;
    KArgs A;
    A.h_dst  = (const float*)d_in[0];
    A.h_src  = (const float*)d_in[1];
    A.h_edge = (const float*)d_in[2];
    A.adj_ma = (const int*)d_in[3];
    A.adj_oo = (const int*)d_in[4];
    // d_in[5] = batch_idxes: arange(B) identity gather.
    A.Wq  = (const float*)d_in[6];
    A.bq  = (const float*)d_in[7];
    A.Wk  = (const float*)d_in[8];
    A.bk  = (const float*)d_in[9];
    A.Wkd = (const float*)d_in[10];
    A.bkd = (const float*)d_in[11];
    A.Wke = (const float*)d_in[12];
    A.bke = (const float*)d_in[13];
    A.Wv  = (const float*)d_in[14];
    A.bv  = (const float*)d_in[15];
    A.Wvd = (const float*)d_in[16];
    A.bvd = (const float*)d_in[17];
    A.Wa  = (const float*)d_in[18];
    A.ba  = (const float*)d_in[19];
    A.rel_pri = (const float*)d_in[20];
    A.rel_att = (const float*)d_in[21];
    A.rel_msg = (const float*)d_in[22];
    A.skip    = (const float*)d_in[23];

    A.qbuf = (float*)ws;                                  // 2 MB
    A.qpk  = (unsigned short*)(ws + 2097152);             // 1 MB
    A.kpk  = (unsigned short*)(ws + 3145728);             // 1.5 MB
    A.vpk  = (unsigned short*)(ws + 4718592);             // 1.5 MB
    A.gelf = (unsigned short*)(ws + 6291456);             // 1 MB
    A.Wab  = (unsigned short*)(ws + 7340032);             // 32 KB
    A.outp = (float*)d_out;

    proj_k<<<1025, 256, 0, stream>>>(A);
    attn_k<<<NB * 16 * H, 256, 0, stream>>>(A);
    out_k<<<NB * 16, 1024, 0, stream>>>(A);
}

// Round 13
// 32.552 us; speedup vs baseline: 1.5482x; 1.5482x over previous
//
#include <hip/hip_runtime.h>
#include <math.h>

#define H 8
#define DK 16
#define OUTC 128
#define INC 64
#define NB 16
#define NN 256
#define NM 128

typedef float f32x4 __attribute__((ext_vector_type(4)));
typedef short s16x4 __attribute__((ext_vector_type(4)));
typedef short s16x8 __attribute__((ext_vector_type(8)));

union U2 { uint2 u; s16x4 s; };

#if __has_builtin(__builtin_amdgcn_mfma_f32_16x16x16bf16_1k)
__device__ __forceinline__ f32x4 MFMA16(s16x4 a, s16x4 b, f32x4 c) {
    return __builtin_amdgcn_mfma_f32_16x16x16bf16_1k(a, b, c, 0, 0, 0);
}
#else
__device__ __forceinline__ f32x4 MFMA16(s16x4 a, s16x4 b, f32x4 c) {
    s16x8 a8 = {a[0], a[1], a[2], a[3], 0, 0, 0, 0};
    s16x8 b8 = {b[0], b[1], b[2], b[3], 0, 0, 0, 0};
    return __builtin_amdgcn_mfma_f32_16x16x32_bf16(a8, b8, c, 0, 0, 0);
}
#endif

__device__ __forceinline__ unsigned short f2bf(float x) {   // RNE
    unsigned int u = __float_as_uint(x);
    return (unsigned short)((u + 0x7fffu + ((u >> 16) & 1u)) >> 16);
}
__device__ __forceinline__ float bf2f(unsigned short s) {
    return __uint_as_float(((unsigned int)s) << 16);
}

struct KArgs {
    const float* h_dst; const float* h_src; const float* h_edge;
    const int* adj_ma; const int* adj_oo;
    const float* Wq; const float* bq; const float* Wk; const float* bk;
    const float* Wkd; const float* bkd; const float* Wke; const float* bke;
    const float* Wv; const float* bv; const float* Wvd; const float* bvd;
    const float* Wa; const float* ba;
    const float* rel_pri; const float* rel_att; const float* rel_msg;
    const float* skip;
    float* qbuf; unsigned short* qpk; unsigned short* kpk; unsigned short* vpk;
    unsigned short* Wab;
    float* outp;
};

// ---------------------------------------------------------------------------
// Kernel 1: projections (512 blocks x 32 rows) + Wab pre-pack (unit 512).
// Wab: bf16 out-GEMM B-frags [ct:8][kt:8][lane:64][4].
// Scales folded: k: dA0*pri0*0.25 | kd: dA1*pri1*0.25 | v: dM0 | c: dM1
// ---------------------------------------------------------------------------
__global__ __launch_bounds__(256) void proj_k(KArgs A)
{
    __shared__ float X_s[32 * 68];
    __shared__ float WT_s[64 * 128];   // (i,o) at i*128 + ((o>>2)^(i&31))*4 + (o&3)

    int t = threadIdx.x;
    int unit = blockIdx.x;

    if (unit >= 512) {
        // ---- Wab pack: Wa -> bf16 B-frags for the fused out-GEMM ----
        #pragma unroll
        for (int it = 0; it < 16; ++it) {
            int flat = t + 256 * it;             // 0..4095 = ct*512 + kt*64 + l
            int ct = flat >> 9, kt = (flat >> 6) & 7, l = flat & 63;
            int co = ct * 16 + (l & 15);
            int kb = kt * 16 + ((l >> 4) << 2);
            float4 wv = *(const float4*)(A.Wa + (long)co * OUTC + kb);
            unsigned int lo = (unsigned int)f2bf(wv.x) | ((unsigned int)f2bf(wv.y) << 16);
            unsigned int hi = (unsigned int)f2bf(wv.z) | ((unsigned int)f2bf(wv.w) << 16);
            ((uint2*)A.Wab)[(ct*8 + kt)*64 + l] = make_uint2(lo, hi);
        }
        return;
    }

    int type, grow0;
    const float *X, *W, *bias;
    if (unit < 128)       { type = 0; grow0 = unit * 32;        X = A.h_dst; W = A.Wq;  bias = A.bq;  }
    else if (unit < 256)  { type = 2; grow0 = (unit-128) * 32;  X = A.h_dst; W = A.Wkd; bias = A.bkd; }
    else if (unit < 384)  { type = 4; grow0 = (unit-256) * 32;  X = A.h_dst; W = A.Wvd; bias = A.bvd; }
    else if (unit < 448)  { type = 1; grow0 = (unit-384) * 32;  X = A.h_src; W = A.Wk;  bias = A.bk;  }
    else                  { type = 3; grow0 = (unit-448) * 32;  X = A.h_src; W = A.Wv;  bias = A.bv;  }

    #pragma unroll
    for (int p = 0; p < 2; ++p) {
        int idx = t + 256 * p;                 // 0..511 float4
        int row = idx >> 4, part = idx & 15;
        float4 v = *(const float4*)(X + (long)(grow0 + row) * INC + part * 4);
        *(float4*)(X_s + row * 68 + part * 4) = v;
    }
    #pragma unroll
    for (int p = 0; p < 8; ++p) {
        int idx = t + 256 * p;
        int o = idx >> 4, part = idx & 15;
        float4 v = *(const float4*)(W + (long)o * INC + part * 4);
        int q0 = o >> 2, ob = o & 3;
        WT_s[(part*4+0)*128 + (((q0 ^ ((part*4+0)&31))<<2) + ob)] = v.x;
        WT_s[(part*4+1)*128 + (((q0 ^ ((part*4+1)&31))<<2) + ob)] = v.y;
        WT_s[(part*4+2)*128 + (((q0 ^ ((part*4+2)&31))<<2) + ob)] = v.z;
        WT_s[(part*4+3)*128 + (((q0 ^ ((part*4+3)&31))<<2) + ob)] = v.w;
    }
    __syncthreads();

    int o4 = t & 31;
    int rq = t >> 5;
    float4 acc[4];
    #pragma unroll
    for (int rr = 0; rr < 4; ++rr) acc[rr] = make_float4(0.f, 0.f, 0.f, 0.f);

    #pragma unroll 4
    for (int i4 = 0; i4 < 16; ++i4) {
        float4 w0 = *(const float4*)(WT_s + (i4*4+0)*128 + ((o4 ^ ((i4*4+0)&31))<<2));
        float4 w1 = *(const float4*)(WT_s + (i4*4+1)*128 + ((o4 ^ ((i4*4+1)&31))<<2));
        float4 w2 = *(const float4*)(WT_s + (i4*4+2)*128 + ((o4 ^ ((i4*4+2)&31))<<2));
        float4 w3 = *(const float4*)(WT_s + (i4*4+3)*128 + ((o4 ^ ((i4*4+3)&31))<<2));
        #pragma unroll
        for (int rr = 0; rr < 4; ++rr) {
            float4 x = *(const float4*)(X_s + (rq + 8*rr) * 68 + i4*4);
            acc[rr].x += x.x*w0.x + x.y*w1.x + x.z*w2.x + x.w*w3.x;
            acc[rr].y += x.x*w0.y + x.y*w1.y + x.z*w2.y + x.w*w3.y;
            acc[rr].z += x.x*w0.z + x.y*w1.z + x.z*w2.z + x.w*w3.z;
            acc[rr].w += x.x*w0.w + x.y*w1.w + x.z*w2.w + x.w*w3.w;
        }
    }

    int obase = o4 * 4;
    int head = o4 >> 2;
    float4 bs = *(const float4*)(bias + obase);
    float scl[4];
    #pragma unroll
    for (int c = 0; c < 4; ++c) {
        int o = obase + c;
        int hh = o >> 4, d = o & 15;
        float v = 1.f;
        if (type == 1)      v = A.rel_pri[hh]     * 0.25f * A.rel_att[(hh*DK + d)*DK + d];
        else if (type == 2) v = A.rel_pri[H + hh] * 0.25f * A.rel_att[((H + hh)*DK + d)*DK + d];
        else if (type == 3) v = A.rel_msg[(hh*DK + d)*DK + d];
        else if (type == 4) v = A.rel_msg[((H + hh)*DK + d)*DK + d];
        scl[c] = v;
    }
    #pragma unroll
    for (int rr = 0; rr < 4; ++rr) {
        int grow = grow0 + rq + 8*rr;
        float4 r4;
        r4.x = (acc[rr].x + bs.x) * scl[0];
        r4.y = (acc[rr].y + bs.y) * scl[1];
        r4.z = (acc[rr].z + bs.z) * scl[2];
        r4.w = (acc[rr].w + bs.w) * scl[3];
        if (type == 0) {
            *(float4*)(A.qbuf + (long)grow * OUTC + obase) = r4;
            unsigned int lo = (unsigned int)f2bf(r4.x) | ((unsigned int)f2bf(r4.y) << 16);
            unsigned int hi = (unsigned int)f2bf(r4.z) | ((unsigned int)f2bf(r4.w) << 16);
            int b = grow >> 8, row = grow & 255;
            int lane = ((o4 & 3) << 4) + (row & 15);
            ((uint2*)A.qpk)[(long)((b*H + head)*16 + (row >> 4)) * 64 + lane] = make_uint2(lo, hi);
        } else if (type == 1 || type == 2) {
            unsigned int lo = (unsigned int)f2bf(r4.x) | ((unsigned int)f2bf(r4.y) << 16);
            unsigned int hi = (unsigned int)f2bf(r4.z) | ((unsigned int)f2bf(r4.w) << 16);
            int b, key;
            if (type == 1) { b = grow >> 7; key = grow & 127; }
            else           { b = grow >> 8; key = 128 + (grow & 255); }
            int lane = (key & 15) + ((o4 & 3) << 4);
            ((uint2*)A.kpk)[(long)((b*H + head)*24 + (key >> 4)) * 64 + lane] = make_uint2(lo, hi);
        } else {
            int b, key;
            if (type == 3) { b = grow >> 7; key = grow & 127; }
            else           { b = grow >> 8; key = 128 + (grow & 255); }
            int tt = key >> 4, lg = (key >> 2) & 3, slot = key & 3;
            int dbase = (o4 & 3) * 4;
            unsigned short* vp = A.vpk + ((long)((b*H + head)*24 + tt) * 64) * 4;
            vp[(lg*16 + dbase+0)*4 + slot] = f2bf(r4.x);
            vp[(lg*16 + dbase+1)*4 + slot] = f2bf(r4.y);
            vp[(lg*16 + dbase+2)*4 + slot] = f2bf(r4.z);
            vp[(lg*16 + dbase+3)*4 + slot] = f2bf(r4.w);
        }
    }
}

// ---------------------------------------------------------------------------
// Kernel 2: fused mask-pack + attention + output GEMM (round-10 structure).
// 256 blocks (b, 16-row chunk) x 1024 threads. Waves (head=w&7, half=w>>3),
// each half does 12 interleaved tiles tt=2i+half, partials via LDS.
// Tweaks: K/V register prefetch; truncation P-pack; Wab B-frags.
// ---------------------------------------------------------------------------
__global__ __launch_bounds__(1024) void attn_out_k(KArgs A)
{
    __shared__ __align__(16) unsigned char smem[37376];
    float* gel_s  = (float*)smem;                       // [16][132]  8448 B
    float* he_s   = (float*)(smem + 8448);              // [128][17]  8704 B
    unsigned long long* mk_s = (unsigned long long*)(smem + 17152); // [16][6] 768 B
    float* s1s2_s = (float*)(smem + 17920);             // [128][2]   1024 B
    float* stats_s= (float*)(smem + 18944);             // [128][4]   2048 B
    float* ocomb  = (float*)(smem + 20992);             // [8][64][4] 8192 B
    float* scomb  = (float*)(smem + 29184);             // [8][64][4] 8192 B

    int t = threadIdx.x;
    int bid = blockIdx.x;
    int b = bid >> 4;
    int chunk = bid & 15;
    int row0 = b * NN + chunk * 16;

    int w = t >> 6, l = t & 63;

    // ---- stage: h_edge ----
    if (t < 512) {
        int q = t >> 5, jc = (t & 31) << 2;
        float4 v = *(const float4*)(A.h_edge + (long)(row0 + q) * NM + jc);
        he_s[(jc+0)*17 + q] = v.x;
        he_s[(jc+1)*17 + q] = v.y;
        he_s[(jc+2)*17 + q] = v.z;
        he_s[(jc+3)*17 + q] = v.w;
    }
    // ---- masks via ballot: wave w packs row w ----
    {
        #pragma unroll
        for (int g = 0; g < 6; ++g) {
            int a = (g < 2) ? A.adj_ma[(long)(row0 + w) * NM + (g << 6) + l]
                            : A.adj_oo[(long)(row0 + w) * NN + ((g - 2) << 6) + l];
            unsigned long long m = __ballot(a != 0);
            if (l == 0) mk_s[w * 6 + g] = m;
        }
    }
    // ---- S1/S2 per (head,row) ----
    if (t < 128) {
        int row = t & 15, hh = t >> 4;
        const float* qr = A.qbuf + (long)(row0 + row) * OUTC + hh * DK;
        float s1 = 0.f, s2 = 0.f;
        #pragma unroll
        for (int d = 0; d < DK; ++d) {
            int o = hh * DK + d;
            float qq = qr[d] * A.rel_att[o * DK + d];
            s1 += qq * A.Wke[o];
            s2 += qq * A.bke[o];
        }
        float sc = A.rel_pri[hh] * 0.25f;
        s1s2_s[(hh*16 + row)*2]     = s1 * sc;
        s1s2_s[(hh*16 + row)*2 + 1] = s2 * sc;
    }
    __syncthreads();

    // ---- attention: 2 waves per head, interleaved tiles ----
    int head = w & 7, half = w >> 3;
    int qi = l & 15;
    int grpb = (l >> 4) << 2;
    int bh = b * H + head;

    U2 qf;
    qf.u = ((const uint2*)A.qpk)[(long)(bh * 16 + chunk) * 64 + l];

    float S1q = s1s2_s[(head*16 + qi)*2], S2q = s1s2_s[(head*16 + qi)*2 + 1];
    unsigned int mdw[12];
    #pragma unroll
    for (int i = 0; i < 12; ++i) mdw[i] = ((const unsigned int*)(mk_s + qi * 6))[i];

    const uint2* kbase = (const uint2*)A.kpk + (long)(bh * 24) * 64;
    const uint2* vbase = (const uint2*)A.vpk + (long)(bh * 24) * 64;

    float sum = 0.f, t0 = 0.f, t1 = 0.f, so = 0.f;
    f32x4 O0 = {0.f, 0.f, 0.f, 0.f};
    f32x4 O1 = {0.f, 0.f, 0.f, 0.f};
    const f32x4 zero = {0.f, 0.f, 0.f, 0.f};
    int sb = (half << 4) + grpb;

    U2 kf, vf;
    kf.u = kbase[half * 64 + l];          // prefetch tile 0
    vf.u = vbase[half * 64 + l];

    #pragma unroll
    for (int i = 0; i < 12; ++i) {
        U2 kn, vn;
        if (i < 11) {                      // prefetch next tile before compute
            int ttn = 2 * (i + 1) + half;
            kn.u = kbase[ttn * 64 + l];
            vn.u = vbase[ttn * 64 + l];
        }
        int tt = 2 * i + half;
        f32x4 s4 = MFMA16(kf.s, qf.s, zero);

        unsigned int dw = mdw[i];
        float ev[4], hev[4];
        #pragma unroll
        for (int r = 0; r < 4; ++r) {
            float x = s4[r];
            if (i < 4) {                   // tt<8 <=> i<4 for both halves
                hev[r] = he_s[(tt * 16 + grpb + r) * 17 + qi];
                x += hev[r] * S1q + S2q;
            }
            float lk = fmaxf(x, 0.1f * x);
            float ex = __expf(lk);
            ev[r] = ((dw >> (sb + r)) & 1u) ? ex : 0.f;
        }
        float es = (ev[0] + ev[1]) + (ev[2] + ev[3]);
        sum += es;
        if (i < 4) {
            t0 += es;
            t1 += (ev[0]*hev[0] + ev[1]*hev[1]) + (ev[2]*hev[2] + ev[3]*hev[3]);
        } else {
            so += es;
        }
        // truncation P-pack (P positive; bf16-trunc err <=0.8%, budget OK)
        unsigned int u0 = __float_as_uint(ev[0]), u1 = __float_as_uint(ev[1]);
        unsigned int u2 = __float_as_uint(ev[2]), u3 = __float_as_uint(ev[3]);
        U2 pp;
        pp.u = make_uint2((u0 >> 16) | (u1 & 0xffff0000u),
                          (u2 >> 16) | (u3 & 0xffff0000u));
        if (i & 1) O1 = MFMA16(pp.s, vf.s, O1);
        else       O0 = MFMA16(pp.s, vf.s, O0);
        if (i < 11) { kf = kn; vf = vn; }
    }
    f32x4 Op = O0 + O1;

    // combine halves via LDS
    if (half) {
        *(f32x4*)(ocomb + (head*64 + l)*4) = Op;
        float4 sc4 = make_float4(sum, t0, t1, so);
        *(float4*)(scomb + (head*64 + l)*4) = sc4;
    }
    __syncthreads();

    if (!half) {
        f32x4 Oo = *(const f32x4*)(ocomb + (head*64 + l)*4);
        float4 sc4 = *(const float4*)(scomb + (head*64 + l)*4);
        f32x4 O = Op + Oo;
        sum += sc4.x; t0 += sc4.y; t1 += sc4.z; so += sc4.w;

        sum += __shfl_xor(sum, 16); sum += __shfl_xor(sum, 32);
        t0  += __shfl_xor(t0, 16);  t0  += __shfl_xor(t0, 32);
        t1  += __shfl_xor(t1, 16);  t1  += __shfl_xor(t1, 32);
        so  += __shfl_xor(so, 16);  so  += __shfl_xor(so, 32);
        if (l < 16) {
            float4 st = make_float4(1.f / sum, t0, t1, so);
            *(float4*)(stats_s + (head * 16 + l) * 4) = st;
        }

        // epilogue: gel -> LDS
        int d = qi;
        int o = head * DK + d;
        float a0 = A.rel_att[o * DK + d];
        float wk = A.Wke[o], bk = A.bke[o];
        #pragma unroll
        for (int r = 0; r < 4; ++r) {
            int ql = grpb + r;
            float4 st = *(const float4*)(stats_s + (head * 16 + ql) * 4);
            int key = 128 + chunk * 16 + ql;
            int tk = key >> 4, lg = (key >> 2) & 3, slot = key & 3;
            float cs = bf2f(A.vpk[(((long)(bh * 24) + tk) * 64 + lg*16 + d) * 4 + slot]);
            float res = st.x * (O[r] + a0 * (wk * st.z + bk * st.y) + st.w * cs);
            gel_s[ql * 132 + o] = 0.5f * res * (1.f + erff(res * 0.70710678118654752f));
        }
    }
    __syncthreads();

    // ---- output GEMM via MFMA: wave = (co-tile head, k-half) ----
    {
        int ct = head, kh = half;
        f32x4 Cp = {0.f, 0.f, 0.f, 0.f};
        #pragma unroll
        for (int kk = 0; kk < 4; ++kk) {
            int kt = kh * 4 + kk;
            float4 ga = *(const float4*)(gel_s + (l & 15) * 132 + kt * 16 + grpb);
            // truncation pack of gel (values O(0.1), err ~0.4%)
            unsigned int g0 = __float_as_uint(ga.x), g1 = __float_as_uint(ga.y);
            unsigned int g2 = __float_as_uint(ga.z), g3 = __float_as_uint(ga.w);
            U2 af, bf;
            af.u = make_uint2((g0 >> 16) | (g1 & 0xffff0000u),
                              (g2 >> 16) | (g3 & 0xffff0000u));
            bf.u = ((const uint2*)A.Wab)[(ct*8 + kt) * 64 + l];
            Cp = MFMA16(af.s, bf.s, Cp);
        }
        if (kh) *(f32x4*)(ocomb + (ct*64 + l)*4) = Cp;
        __syncthreads();
        if (!kh) {
            f32x4 Co = *(const f32x4*)(ocomb + (ct*64 + l)*4);
            Cp = Cp + Co;
            float alpha = 1.f / (1.f + __expf(-A.skip[0]));
            float beta = 1.f - alpha;
            int co = ct * 16 + (l & 15);
            float bias = A.ba[co];
            #pragma unroll
            for (int r = 0; r < 4; ++r) {
                long grow = row0 + grpb + r;
                float q0 = A.qbuf[grow * OUTC + co];
                A.outp[grow * OUTC + co] = alpha * (Cp[r] + bias) + beta * q0;
            }
        }
    }
}

extern "C" void kernel_launch(void* const* d_in, const int* in_sizes, int n_in,
                              void* d_out, int out_size, void* d_ws, size_t ws_size,
                              hipStream_t stream) {
    char* ws = (char*)d_ws;
    KArgs A;
    A.h_dst  = (const float*)d_in[0];
    A.h_src  = (const float*)d_in[1];
    A.h_edge = (const float*)d_in[2];
    A.adj_ma = (const int*)d_in[3];
    A.adj_oo = (const int*)d_in[4];
    // d_in[5] = batch_idxes: arange(B) identity gather.
    A.Wq  = (const float*)d_in[6];
    A.bq  = (const float*)d_in[7];
    A.Wk  = (const float*)d_in[8];
    A.bk  = (const float*)d_in[9];
    A.Wkd = (const float*)d_in[10];
    A.bkd = (const float*)d_in[11];
    A.Wke = (const float*)d_in[12];
    A.bke = (const float*)d_in[13];
    A.Wv  = (const float*)d_in[14];
    A.bv  = (const float*)d_in[15];
    A.Wvd = (const float*)d_in[16];
    A.bvd = (const float*)d_in[17];
    A.Wa  = (const float*)d_in[18];
    A.ba  = (const float*)d_in[19];
    A.rel_pri = (const float*)d_in[20];
    A.rel_att = (const float*)d_in[21];
    A.rel_msg = (const float*)d_in[22];
    A.skip    = (const float*)d_in[23];

    A.qbuf = (float*)ws;                                  // 2 MB
    A.qpk  = (unsigned short*)(ws + 2097152);             // 1 MB
    A.kpk  = (unsigned short*)(ws + 3145728);             // 1.5 MB
    A.vpk  = (unsigned short*)(ws + 4718592);             // 1.5 MB
    A.Wab  = (unsigned short*)(ws + 6291456);             // 32 KB
    A.outp = (float*)d_out;

    proj_k<<<513, 256, 0, stream>>>(A);
    attn_out_k<<<NB * 16, 1024, 0, stream>>>(A);
}

// Round 14
// 31.904 us; speedup vs baseline: 1.5797x; 1.0203x over previous
//
#include <hip/hip_runtime.h>
#include <math.h>

#define H 8
#define DK 16
#define OUTC 128
#define INC 64
#define NB 16
#define NN 256
#define NM 128

typedef float f32x4 __attribute__((ext_vector_type(4)));
typedef short s16x4 __attribute__((ext_vector_type(4)));
typedef short s16x8 __attribute__((ext_vector_type(8)));

union U2 { uint2 u; s16x4 s; };

#if __has_builtin(__builtin_amdgcn_mfma_f32_16x16x16bf16_1k)
__device__ __forceinline__ f32x4 MFMA16(s16x4 a, s16x4 b, f32x4 c) {
    return __builtin_amdgcn_mfma_f32_16x16x16bf16_1k(a, b, c, 0, 0, 0);
}
#else
__device__ __forceinline__ f32x4 MFMA16(s16x4 a, s16x4 b, f32x4 c) {
    s16x8 a8 = {a[0], a[1], a[2], a[3], 0, 0, 0, 0};
    s16x8 b8 = {b[0], b[1], b[2], b[3], 0, 0, 0, 0};
    return __builtin_amdgcn_mfma_f32_16x16x32_bf16(a8, b8, c, 0, 0, 0);
}
#endif

__device__ __forceinline__ unsigned short f2bf(float x) {   // RNE
    unsigned int u = __float_as_uint(x);
    return (unsigned short)((u + 0x7fffu + ((u >> 16) & 1u)) >> 16);
}
__device__ __forceinline__ float bf2f(unsigned short s) {
    return __uint_as_float(((unsigned int)s) << 16);
}

struct KArgs {
    const float* h_dst; const float* h_src; const float* h_edge;
    const int* adj_ma; const int* adj_oo;
    const float* Wq; const float* bq; const float* Wk; const float* bk;
    const float* Wkd; const float* bkd; const float* Wke; const float* bke;
    const float* Wv; const float* bv; const float* Wvd; const float* bvd;
    const float* Wa; const float* ba;
    const float* rel_pri; const float* rel_att; const float* rel_msg;
    const float* skip;
    float* qbuf; unsigned short* qpk; unsigned short* kpk; unsigned short* vpk;
    unsigned short* Wab;
    float* outp;
};

// ---------------------------------------------------------------------------
// Kernel 1: projections (512 blocks x 32 rows) + Wab pre-pack (unit 512).
// Wab: bf16 out-GEMM B-frags [ct:8][kt:8][lane:64][4].
// Scales folded: k: dA0*pri0*0.25 | kd: dA1*pri1*0.25 | v: dM0 | c: dM1
// ---------------------------------------------------------------------------
__global__ __launch_bounds__(256) void proj_k(KArgs A)
{
    __shared__ float X_s[32 * 68];
    __shared__ float WT_s[64 * 128];   // (i,o) at i*128 + ((o>>2)^(i&31))*4 + (o&3)

    int t = threadIdx.x;
    int unit = blockIdx.x;

    if (unit >= 512) {
        // ---- Wab pack: Wa -> bf16 B-frags for the fused out-GEMM ----
        #pragma unroll
        for (int it = 0; it < 16; ++it) {
            int flat = t + 256 * it;             // 0..4095 = ct*512 + kt*64 + l
            int ct = flat >> 9, kt = (flat >> 6) & 7, l = flat & 63;
            int co = ct * 16 + (l & 15);
            int kb = kt * 16 + ((l >> 4) << 2);
            float4 wv = *(const float4*)(A.Wa + (long)co * OUTC + kb);
            unsigned int lo = (unsigned int)f2bf(wv.x) | ((unsigned int)f2bf(wv.y) << 16);
            unsigned int hi = (unsigned int)f2bf(wv.z) | ((unsigned int)f2bf(wv.w) << 16);
            ((uint2*)A.Wab)[(ct*8 + kt)*64 + l] = make_uint2(lo, hi);
        }
        return;
    }

    int type, grow0;
    const float *X, *W, *bias;
    if (unit < 128)       { type = 0; grow0 = unit * 32;        X = A.h_dst; W = A.Wq;  bias = A.bq;  }
    else if (unit < 256)  { type = 2; grow0 = (unit-128) * 32;  X = A.h_dst; W = A.Wkd; bias = A.bkd; }
    else if (unit < 384)  { type = 4; grow0 = (unit-256) * 32;  X = A.h_dst; W = A.Wvd; bias = A.bvd; }
    else if (unit < 448)  { type = 1; grow0 = (unit-384) * 32;  X = A.h_src; W = A.Wk;  bias = A.bk;  }
    else                  { type = 3; grow0 = (unit-448) * 32;  X = A.h_src; W = A.Wv;  bias = A.bv;  }

    #pragma unroll
    for (int p = 0; p < 2; ++p) {
        int idx = t + 256 * p;                 // 0..511 float4
        int row = idx >> 4, part = idx & 15;
        float4 v = *(const float4*)(X + (long)(grow0 + row) * INC + part * 4);
        *(float4*)(X_s + row * 68 + part * 4) = v;
    }
    #pragma unroll
    for (int p = 0; p < 8; ++p) {
        int idx = t + 256 * p;
        int o = idx >> 4, part = idx & 15;
        float4 v = *(const float4*)(W + (long)o * INC + part * 4);
        int q0 = o >> 2, ob = o & 3;
        WT_s[(part*4+0)*128 + (((q0 ^ ((part*4+0)&31))<<2) + ob)] = v.x;
        WT_s[(part*4+1)*128 + (((q0 ^ ((part*4+1)&31))<<2) + ob)] = v.y;
        WT_s[(part*4+2)*128 + (((q0 ^ ((part*4+2)&31))<<2) + ob)] = v.z;
        WT_s[(part*4+3)*128 + (((q0 ^ ((part*4+3)&31))<<2) + ob)] = v.w;
    }
    __syncthreads();

    int o4 = t & 31;
    int rq = t >> 5;
    float4 acc[4];
    #pragma unroll
    for (int rr = 0; rr < 4; ++rr) acc[rr] = make_float4(0.f, 0.f, 0.f, 0.f);

    #pragma unroll 4
    for (int i4 = 0; i4 < 16; ++i4) {
        float4 w0 = *(const float4*)(WT_s + (i4*4+0)*128 + ((o4 ^ ((i4*4+0)&31))<<2));
        float4 w1 = *(const float4*)(WT_s + (i4*4+1)*128 + ((o4 ^ ((i4*4+1)&31))<<2));
        float4 w2 = *(const float4*)(WT_s + (i4*4+2)*128 + ((o4 ^ ((i4*4+2)&31))<<2));
        float4 w3 = *(const float4*)(WT_s + (i4*4+3)*128 + ((o4 ^ ((i4*4+3)&31))<<2));
        #pragma unroll
        for (int rr = 0; rr < 4; ++rr) {
            float4 x = *(const float4*)(X_s + (rq + 8*rr) * 68 + i4*4);
            acc[rr].x += x.x*w0.x + x.y*w1.x + x.z*w2.x + x.w*w3.x;
            acc[rr].y += x.x*w0.y + x.y*w1.y + x.z*w2.y + x.w*w3.y;
            acc[rr].z += x.x*w0.z + x.y*w1.z + x.z*w2.z + x.w*w3.z;
            acc[rr].w += x.x*w0.w + x.y*w1.w + x.z*w2.w + x.w*w3.w;
        }
    }

    int obase = o4 * 4;
    int head = o4 >> 2;
    float4 bs = *(const float4*)(bias + obase);
    float scl[4];
    #pragma unroll
    for (int c = 0; c < 4; ++c) {
        int o = obase + c;
        int hh = o >> 4, d = o & 15;
        float v = 1.f;
        if (type == 1)      v = A.rel_pri[hh]     * 0.25f * A.rel_att[(hh*DK + d)*DK + d];
        else if (type == 2) v = A.rel_pri[H + hh] * 0.25f * A.rel_att[((H + hh)*DK + d)*DK + d];
        else if (type == 3) v = A.rel_msg[(hh*DK + d)*DK + d];
        else if (type == 4) v = A.rel_msg[((H + hh)*DK + d)*DK + d];
        scl[c] = v;
    }
    #pragma unroll
    for (int rr = 0; rr < 4; ++rr) {
        int grow = grow0 + rq + 8*rr;
        float4 r4;
        r4.x = (acc[rr].x + bs.x) * scl[0];
        r4.y = (acc[rr].y + bs.y) * scl[1];
        r4.z = (acc[rr].z + bs.z) * scl[2];
        r4.w = (acc[rr].w + bs.w) * scl[3];
        if (type == 0) {
            *(float4*)(A.qbuf + (long)grow * OUTC + obase) = r4;
            unsigned int lo = (unsigned int)f2bf(r4.x) | ((unsigned int)f2bf(r4.y) << 16);
            unsigned int hi = (unsigned int)f2bf(r4.z) | ((unsigned int)f2bf(r4.w) << 16);
            int b = grow >> 8, row = grow & 255;
            int lane = ((o4 & 3) << 4) + (row & 15);
            ((uint2*)A.qpk)[(long)((b*H + head)*16 + (row >> 4)) * 64 + lane] = make_uint2(lo, hi);
        } else if (type == 1 || type == 2) {
            unsigned int lo = (unsigned int)f2bf(r4.x) | ((unsigned int)f2bf(r4.y) << 16);
            unsigned int hi = (unsigned int)f2bf(r4.z) | ((unsigned int)f2bf(r4.w) << 16);
            int b, key;
            if (type == 1) { b = grow >> 7; key = grow & 127; }
            else           { b = grow >> 8; key = 128 + (grow & 255); }
            int lane = (key & 15) + ((o4 & 3) << 4);
            ((uint2*)A.kpk)[(long)((b*H + head)*24 + (key >> 4)) * 64 + lane] = make_uint2(lo, hi);
        } else {
            int b, key;
            if (type == 3) { b = grow >> 7; key = grow & 127; }
            else           { b = grow >> 8; key = 128 + (grow & 255); }
            int tt = key >> 4, lg = (key >> 2) & 3, slot = key & 3;
            int dbase = (o4 & 3) * 4;
            unsigned short* vp = A.vpk + ((long)((b*H + head)*24 + tt) * 64) * 4;
            vp[(lg*16 + dbase+0)*4 + slot] = f2bf(r4.x);
            vp[(lg*16 + dbase+1)*4 + slot] = f2bf(r4.y);
            vp[(lg*16 + dbase+2)*4 + slot] = f2bf(r4.z);
            vp[(lg*16 + dbase+3)*4 + slot] = f2bf(r4.w);
        }
    }
}

// ---------------------------------------------------------------------------
// Kernel 2: fused mask-pack + attention + output GEMM (round-13 structure).
// Round-14 tweaks (latency hiding only): hoisted adj loads before ballots;
// K/V fragment prefetch deepened to 2 tiles ahead (3-slot register ring).
// ---------------------------------------------------------------------------
__global__ __launch_bounds__(1024) void attn_out_k(KArgs A)
{
    __shared__ __align__(16) unsigned char smem[37376];
    float* gel_s  = (float*)smem;                       // [16][132]  8448 B
    float* he_s   = (float*)(smem + 8448);              // [128][17]  8704 B
    unsigned long long* mk_s = (unsigned long long*)(smem + 17152); // [16][6] 768 B
    float* s1s2_s = (float*)(smem + 17920);             // [128][2]   1024 B
    float* stats_s= (float*)(smem + 18944);             // [128][4]   2048 B
    float* ocomb  = (float*)(smem + 20992);             // [8][64][4] 8192 B
    float* scomb  = (float*)(smem + 29184);             // [8][64][4] 8192 B

    int t = threadIdx.x;
    int bid = blockIdx.x;
    int b = bid >> 4;
    int chunk = bid & 15;
    int row0 = b * NN + chunk * 16;

    int w = t >> 6, l = t & 63;

    // ---- masks: hoist all 6 adj loads (pipelined), then ballot ----
    {
        int a6[6];
        #pragma unroll
        for (int g = 0; g < 6; ++g)
            a6[g] = (g < 2) ? A.adj_ma[(long)(row0 + w) * NM + (g << 6) + l]
                            : A.adj_oo[(long)(row0 + w) * NN + ((g - 2) << 6) + l];
        // ---- stage: h_edge (overlaps adj latency) ----
        if (t < 512) {
            int q = t >> 5, jc = (t & 31) << 2;
            float4 v = *(const float4*)(A.h_edge + (long)(row0 + q) * NM + jc);
            he_s[(jc+0)*17 + q] = v.x;
            he_s[(jc+1)*17 + q] = v.y;
            he_s[(jc+2)*17 + q] = v.z;
            he_s[(jc+3)*17 + q] = v.w;
        }
        #pragma unroll
        for (int g = 0; g < 6; ++g) {
            unsigned long long m = __ballot(a6[g] != 0);
            if (l == 0) mk_s[w * 6 + g] = m;
        }
    }
    // ---- S1/S2 per (head,row) ----
    if (t < 128) {
        int row = t & 15, hh = t >> 4;
        const float* qr = A.qbuf + (long)(row0 + row) * OUTC + hh * DK;
        float s1 = 0.f, s2 = 0.f;
        #pragma unroll
        for (int d = 0; d < DK; ++d) {
            int o = hh * DK + d;
            float qq = qr[d] * A.rel_att[o * DK + d];
            s1 += qq * A.Wke[o];
            s2 += qq * A.bke[o];
        }
        float sc = A.rel_pri[hh] * 0.25f;
        s1s2_s[(hh*16 + row)*2]     = s1 * sc;
        s1s2_s[(hh*16 + row)*2 + 1] = s2 * sc;
    }
    __syncthreads();

    // ---- attention: 2 waves per head, interleaved tiles ----
    int head = w & 7, half = w >> 3;
    int qi = l & 15;
    int grpb = (l >> 4) << 2;
    int bh = b * H + head;

    U2 qf;
    qf.u = ((const uint2*)A.qpk)[(long)(bh * 16 + chunk) * 64 + l];

    float S1q = s1s2_s[(head*16 + qi)*2], S2q = s1s2_s[(head*16 + qi)*2 + 1];
    unsigned int mdw[12];
    #pragma unroll
    for (int i = 0; i < 12; ++i) mdw[i] = ((const unsigned int*)(mk_s + qi * 6))[i];

    const uint2* kbase = (const uint2*)A.kpk + (long)(bh * 24) * 64;
    const uint2* vbase = (const uint2*)A.vpk + (long)(bh * 24) * 64;

    float sum = 0.f, t0 = 0.f, t1 = 0.f, so = 0.f;
    f32x4 O0 = {0.f, 0.f, 0.f, 0.f};
    f32x4 O1 = {0.f, 0.f, 0.f, 0.f};
    const f32x4 zero = {0.f, 0.f, 0.f, 0.f};
    int sb = (half << 4) + grpb;

    // 3-slot register ring, prefetch depth 2
    U2 kb[3], vb[3];
    kb[0].u = kbase[(0 + half) * 64 + l];
    vb[0].u = vbase[(0 + half) * 64 + l];
    kb[1].u = kbase[(2 + half) * 64 + l];
    vb[1].u = vbase[(2 + half) * 64 + l];

    #pragma unroll
    for (int i = 0; i < 12; ++i) {
        if (i < 10) {                      // prefetch tile i+2
            int ttn = 2 * (i + 2) + half;
            kb[(i + 2) % 3].u = kbase[ttn * 64 + l];
            vb[(i + 2) % 3].u = vbase[ttn * 64 + l];
        }
        U2 kf = kb[i % 3], vf = vb[i % 3];
        int tt = 2 * i + half;
        f32x4 s4 = MFMA16(kf.s, qf.s, zero);

        unsigned int dw = mdw[i];
        float ev[4], hev[4];
        #pragma unroll
        for (int r = 0; r < 4; ++r) {
            float x = s4[r];
            if (i < 4) {                   // tt<8 <=> i<4 for both halves
                hev[r] = he_s[(tt * 16 + grpb + r) * 17 + qi];
                x += hev[r] * S1q + S2q;
            }
            float lk = fmaxf(x, 0.1f * x);
            float ex = __expf(lk);
            ev[r] = ((dw >> (sb + r)) & 1u) ? ex : 0.f;
        }
        float es = (ev[0] + ev[1]) + (ev[2] + ev[3]);
        sum += es;
        if (i < 4) {
            t0 += es;
            t1 += (ev[0]*hev[0] + ev[1]*hev[1]) + (ev[2]*hev[2] + ev[3]*hev[3]);
        } else {
            so += es;
        }
        // truncation P-pack (P positive; bf16-trunc err <=0.8%, budget OK)
        unsigned int u0 = __float_as_uint(ev[0]), u1 = __float_as_uint(ev[1]);
        unsigned int u2 = __float_as_uint(ev[2]), u3 = __float_as_uint(ev[3]);
        U2 pp;
        pp.u = make_uint2((u0 >> 16) | (u1 & 0xffff0000u),
                          (u2 >> 16) | (u3 & 0xffff0000u));
        if (i & 1) O1 = MFMA16(pp.s, vf.s, O1);
        else       O0 = MFMA16(pp.s, vf.s, O0);
    }
    f32x4 Op = O0 + O1;

    // combine halves via LDS
    if (half) {
        *(f32x4*)(ocomb + (head*64 + l)*4) = Op;
        float4 sc4 = make_float4(sum, t0, t1, so);
        *(float4*)(scomb + (head*64 + l)*4) = sc4;
    }
    __syncthreads();

    if (!half) {
        f32x4 Oo = *(const f32x4*)(ocomb + (head*64 + l)*4);
        float4 sc4 = *(const float4*)(scomb + (head*64 + l)*4);
        f32x4 O = Op + Oo;
        sum += sc4.x; t0 += sc4.y; t1 += sc4.z; so += sc4.w;

        sum += __shfl_xor(sum, 16); sum += __shfl_xor(sum, 32);
        t0  += __shfl_xor(t0, 16);  t0  += __shfl_xor(t0, 32);
        t1  += __shfl_xor(t1, 16);  t1  += __shfl_xor(t1, 32);
        so  += __shfl_xor(so, 16);  so  += __shfl_xor(so, 32);
        if (l < 16) {
            float4 st = make_float4(1.f / sum, t0, t1, so);
            *(float4*)(stats_s + (head * 16 + l) * 4) = st;
        }

        // epilogue: gel -> LDS
        int d = qi;
        int o = head * DK + d;
        float a0 = A.rel_att[o * DK + d];
        float wk = A.Wke[o], bk = A.bke[o];
        #pragma unroll
        for (int r = 0; r < 4; ++r) {
            int ql = grpb + r;
            float4 st = *(const float4*)(stats_s + (head * 16 + ql) * 4);
            int key = 128 + chunk * 16 + ql;
            int tk = key >> 4, lg = (key >> 2) & 3, slot = key & 3;
            float cs = bf2f(A.vpk[(((long)(bh * 24) + tk) * 64 + lg*16 + d) * 4 + slot]);
            float res = st.x * (O[r] + a0 * (wk * st.z + bk * st.y) + st.w * cs);
            gel_s[ql * 132 + o] = 0.5f * res * (1.f + erff(res * 0.70710678118654752f));
        }
    }
    __syncthreads();

    // ---- output GEMM via MFMA: wave = (co-tile head, k-half) ----
    {
        int ct = head, kh = half;
        f32x4 Cp = {0.f, 0.f, 0.f, 0.f};
        #pragma unroll
        for (int kk = 0; kk < 4; ++kk) {
            int kt = kh * 4 + kk;
            float4 ga = *(const float4*)(gel_s + (l & 15) * 132 + kt * 16 + grpb);
            // truncation pack of gel (values O(0.1), err ~0.4%)
            unsigned int g0 = __float_as_uint(ga.x), g1 = __float_as_uint(ga.y);
            unsigned int g2 = __float_as_uint(ga.z), g3 = __float_as_uint(ga.w);
            U2 af, bf;
            af.u = make_uint2((g0 >> 16) | (g1 & 0xffff0000u),
                              (g2 >> 16) | (g3 & 0xffff0000u));
            bf.u = ((const uint2*)A.Wab)[(ct*8 + kt) * 64 + l];
            Cp = MFMA16(af.s, bf.s, Cp);
        }
        if (kh) *(f32x4*)(ocomb + (ct*64 + l)*4) = Cp;
        __syncthreads();
        if (!kh) {
            f32x4 Co = *(const f32x4*)(ocomb + (ct*64 + l)*4);
            Cp = Cp + Co;
            float alpha = 1.f / (1.f + __expf(-A.skip[0]));
            float beta = 1.f - alpha;
            int co = ct * 16 + (l & 15);
            float bias = A.ba[co];
            #pragma unroll
            for (int r = 0; r < 4; ++r) {
                long grow = row0 + grpb + r;
                float q0 = A.qbuf[grow * OUTC + co];
                A.outp[grow * OUTC + co] = alpha * (Cp[r] + bias) + beta * q0;
            }
        }
    }
}

extern "C" void kernel_launch(void* const* d_in, const int* in_sizes, int n_in,
                              void* d_out, int out_size, void* d_ws, size_t ws_size,
                              hipStream_t stream) {
    char* ws = (char*)d_ws;
    KArgs A;
    A.h_dst  = (const float*)d_in[0];
    A.h_src  = (const float*)d_in[1];
    A.h_edge = (const float*)d_in[2];
    A.adj_ma = (const int*)d_in[3];
    A.adj_oo = (const int*)d_in[4];
    // d_in[5] = batch_idxes: arange(B) identity gather.
    A.Wq  = (const float*)d_in[6];
    A.bq  = (const float*)d_in[7];
    A.Wk  = (const float*)d_in[8];
    A.bk  = (const float*)d_in[9];
    A.Wkd = (const float*)d_in[10];
    A.bkd = (const float*)d_in[11];
    A.Wke = (const float*)d_in[12];
    A.bke = (const float*)d_in[13];
    A.Wv  = (const float*)d_in[14];
    A.bv  = (const float*)d_in[15];
    A.Wvd = (const float*)d_in[16];
    A.bvd = (const float*)d_in[17];
    A.Wa  = (const float*)d_in[18];
    A.ba  = (const float*)d_in[19];
    A.rel_pri = (const float*)d_in[20];
    A.rel_att = (const float*)d_in[21];
    A.rel_msg = (const float*)d_in[22];
    A.skip    = (const float*)d_in[23];

    A.qbuf = (float*)ws;                                  // 2 MB
    A.qpk  = (unsigned short*)(ws + 2097152);             // 1 MB
    A.kpk  = (unsigned short*)(ws + 3145728);             // 1.5 MB
    A.vpk  = (unsigned short*)(ws + 4718592);             // 1.5 MB
    A.Wab  = (unsigned short*)(ws + 6291456);             // 32 KB
    A.outp = (float*)d_out;

    proj_k<<<513, 256, 0, stream>>>(A);
    attn_out_k<<<NB * 16, 1024, 0, stream>>>(A);
}